// Round 3
// baseline (724.440 us; speedup 1.0000x reference)
//
#include <hip/hip_runtime.h>
#include <hip/hip_bf16.h>

// ---------- helpers ----------
__device__ inline float bf2f(unsigned int u16) {
    union { unsigned int i; float f; } v;
    v.i = u16 << 16;
    return v.f;
}
__device__ inline unsigned int f2bf(float f) {
    union { float f; unsigned int i; } v;
    v.f = f;
    return (v.i + 0x7FFFu + ((v.i >> 16) & 1u)) >> 16;   // RNE
}

// ---------- node-level GEMM: out[M,Kout] = act(A[M,256] @ W[256,Kout] + bias) ----------
template<int TILE_M, bool BIAS, bool RELU, bool OUTBF16>
__global__ __launch_bounds__(256) void gemm_k256(
    const float* __restrict__ A, const float* __restrict__ W,
    const float* __restrict__ bias, void* __restrict__ out,
    int M, int Kout)
{
    __shared__ float lds[TILE_M * 256];
    const int tid  = threadIdx.x;
    const int row0 = blockIdx.x * TILE_M;
    const int j    = blockIdx.y * 256 + tid;

    const int tile_elems = TILE_M * 256;
    for (int i = tid; i < tile_elems; i += 256) {
        int r = i >> 8;
        lds[i] = (row0 + r < M) ? A[(size_t)row0 * 256 + i] : 0.0f;
    }
    __syncthreads();

    float acc[TILE_M];
#pragma unroll
    for (int r = 0; r < TILE_M; ++r) acc[r] = 0.0f;

    const float* Wp = W + j;
    for (int d = 0; d < 256; d += 4) {
        const float w0 = Wp[(size_t)(d + 0) * Kout];
        const float w1 = Wp[(size_t)(d + 1) * Kout];
        const float w2 = Wp[(size_t)(d + 2) * Kout];
        const float w3 = Wp[(size_t)(d + 3) * Kout];
#pragma unroll
        for (int r = 0; r < TILE_M; ++r) {
            const float4 av = *(const float4*)&lds[r * 256 + d];
            acc[r] = fmaf(av.w, w3, fmaf(av.z, w2, fmaf(av.y, w1, fmaf(av.x, w0, acc[r]))));
        }
    }

    const float b = BIAS ? bias[j] : 0.0f;
#pragma unroll
    for (int r = 0; r < TILE_M; ++r) {
        if (row0 + r >= M) break;
        float v = acc[r] + b;
        if (RELU) v = fmaxf(v, 0.0f);
        const size_t idx = (size_t)(row0 + r) * Kout + j;
        if (OUTBF16) ((unsigned short*)out)[idx] = (unsigned short)f2bf(v);
        else         ((float*)out)[idx] = v;
    }
}

// ---------- fused MLP + predictor: gp[M,512] = bf16( (relu(z@W1+b1)@W2+b2) @ Wpred ) ----------
template<int TILE_M>
__global__ __launch_bounds__(256) void fused_mlp_pred(
    const float* __restrict__ z,
    const float* __restrict__ W1, const float* __restrict__ b1,
    const float* __restrict__ W2, const float* __restrict__ b2,
    const float* __restrict__ Wpred,
    unsigned short* __restrict__ gp, int M)
{
    __shared__ float zt[TILE_M * 256];   // z tile, later reused as g tile
    __shared__ float tt[TILE_M * 256];   // t = relu(z@W1+b1) tile
    const int tid  = threadIdx.x;
    const int row0 = blockIdx.x * TILE_M;

    for (int i = tid; i < TILE_M * 256; i += 256) {
        int r = i >> 8;
        zt[i] = (row0 + r < M) ? z[(size_t)row0 * 256 + i] : 0.0f;
    }
    __syncthreads();

    // phase 1: t[., tid] = relu(z @ W1 + b1)
    {
        float acc[TILE_M];
#pragma unroll
        for (int r = 0; r < TILE_M; ++r) acc[r] = 0.0f;
        const float* Wp = W1 + tid;
        for (int d = 0; d < 256; d += 4) {
            const float w0 = Wp[(d + 0) * 256];
            const float w1 = Wp[(d + 1) * 256];
            const float w2 = Wp[(d + 2) * 256];
            const float w3 = Wp[(d + 3) * 256];
#pragma unroll
            for (int r = 0; r < TILE_M; ++r) {
                const float4 av = *(const float4*)&zt[r * 256 + d];
                acc[r] = fmaf(av.w, w3, fmaf(av.z, w2, fmaf(av.y, w1, fmaf(av.x, w0, acc[r]))));
            }
        }
        const float b = b1[tid];
#pragma unroll
        for (int r = 0; r < TILE_M; ++r) tt[r * 256 + tid] = fmaxf(acc[r] + b, 0.0f);
    }
    __syncthreads();

    // phase 2: g[., tid] = t @ W2 + b2  -> overwrite zt
    {
        float acc[TILE_M];
#pragma unroll
        for (int r = 0; r < TILE_M; ++r) acc[r] = 0.0f;
        const float* Wp = W2 + tid;
        for (int d = 0; d < 256; d += 4) {
            const float w0 = Wp[(d + 0) * 256];
            const float w1 = Wp[(d + 1) * 256];
            const float w2 = Wp[(d + 2) * 256];
            const float w3 = Wp[(d + 3) * 256];
#pragma unroll
            for (int r = 0; r < TILE_M; ++r) {
                const float4 av = *(const float4*)&tt[r * 256 + d];
                acc[r] = fmaf(av.w, w3, fmaf(av.z, w2, fmaf(av.y, w1, fmaf(av.x, w0, acc[r]))));
            }
        }
        const float b = b2[tid];
        __syncthreads();
#pragma unroll
        for (int r = 0; r < TILE_M; ++r) zt[r * 256 + tid] = acc[r] + b;
    }
    __syncthreads();

    // phase 3: gp[., tid] and gp[., 256+tid] = g @ Wpred (bf16 out)
    {
        float acc0[TILE_M], acc1[TILE_M];
#pragma unroll
        for (int r = 0; r < TILE_M; ++r) { acc0[r] = 0.0f; acc1[r] = 0.0f; }
        const float* Wp0 = Wpred + tid;
        const float* Wp1 = Wpred + 256 + tid;
        for (int d = 0; d < 256; d += 4) {
            const float a0 = Wp0[(size_t)(d + 0) * 512], c0 = Wp1[(size_t)(d + 0) * 512];
            const float a1 = Wp0[(size_t)(d + 1) * 512], c1 = Wp1[(size_t)(d + 1) * 512];
            const float a2 = Wp0[(size_t)(d + 2) * 512], c2 = Wp1[(size_t)(d + 2) * 512];
            const float a3 = Wp0[(size_t)(d + 3) * 512], c3 = Wp1[(size_t)(d + 3) * 512];
#pragma unroll
            for (int r = 0; r < TILE_M; ++r) {
                const float4 gv = *(const float4*)&zt[r * 256 + d];
                acc0[r] = fmaf(gv.w, a3, fmaf(gv.z, a2, fmaf(gv.y, a1, fmaf(gv.x, a0, acc0[r]))));
                acc1[r] = fmaf(gv.w, c3, fmaf(gv.z, c2, fmaf(gv.y, c1, fmaf(gv.x, c0, acc1[r]))));
            }
        }
#pragma unroll
        for (int r = 0; r < TILE_M; ++r) {
            if (row0 + r >= M) break;
            const size_t base = (size_t)(row0 + r) * 512;
            gp[base + tid]       = (unsigned short)f2bf(acc0[r]);
            gp[base + 256 + tid] = (unsigned short)f2bf(acc1[r]);
        }
    }
}

// ---------- per-edge attention scalar: a[e] = sigmoid(q[c].k[s]) ----------
__global__ __launch_bounds__(256) void edge_dot(
    const unsigned short* __restrict__ qb, const unsigned short* __restrict__ kb,
    const int* __restrict__ edge_src, const int* __restrict__ node_ids,
    const int* __restrict__ masked_idx, const int* __restrict__ edge_idx,
    float* __restrict__ a_out, int P)
{
    const int wave = threadIdx.x >> 6;
    const int lane = threadIdx.x & 63;
    const int e = blockIdx.x * 4 + wave;
    if (e >= P) return;

    const int c = node_ids[masked_idx[e]];
    const int s = edge_src[edge_idx[e]];

    const uint2 qv = *(const uint2*)&qb[(size_t)c * 256 + lane * 4];
    const uint2 kv = *(const uint2*)&kb[(size_t)s * 256 + lane * 4];
    float dot = bf2f(qv.x & 0xFFFFu) * bf2f(kv.x & 0xFFFFu)
              + bf2f(qv.x >> 16)     * bf2f(kv.x >> 16)
              + bf2f(qv.y & 0xFFFFu) * bf2f(kv.y & 0xFFFFu)
              + bf2f(qv.y >> 16)     * bf2f(kv.y >> 16);
#pragma unroll
    for (int off = 32; off; off >>= 1) dot += __shfl_xor(dot, off, 64);

    if (lane == 0) a_out[e] = 1.0f / (1.0f + expf(-dot));
}

// ---------- edge combine: out[e,:] = a*hp[c,:] + (1-a)*gp[s,:] + bpred, f32 out ----------
__global__ __launch_bounds__(256) void edge_combine(
    const float* __restrict__ a_arr,
    const unsigned short* __restrict__ hp, const unsigned short* __restrict__ gp,
    const float* __restrict__ bpred,
    const int* __restrict__ edge_src, const int* __restrict__ node_ids,
    const int* __restrict__ masked_idx, const int* __restrict__ edge_idx,
    float* __restrict__ out, int P)
{
    const int wave = threadIdx.x >> 6;
    const int lane = threadIdx.x & 63;
    const int e = blockIdx.x * 4 + wave;
    if (e >= P) return;

    const int mi = masked_idx[e];
    const int c  = node_ids[mi];
    const int s  = edge_src[edge_idx[e]];

    const float a = a_arr[e];
    const float oma = 1.0f - a;

    const uint4 hv = *(const uint4*)&hp[(size_t)c * 512 + lane * 8];
    const uint4 gv = *(const uint4*)&gp[(size_t)s * 512 + lane * 8];
    const float4 bp0 = *(const float4*)&bpred[lane * 8];
    const float4 bp1 = *(const float4*)&bpred[lane * 8 + 4];

    const unsigned int hw[4] = {hv.x, hv.y, hv.z, hv.w};
    const unsigned int gw[4] = {gv.x, gv.y, gv.z, gv.w};
    const float bp[8] = {bp0.x, bp0.y, bp0.z, bp0.w, bp1.x, bp1.y, bp1.z, bp1.w};

    float res[8];
#pragma unroll
    for (int i = 0; i < 4; ++i) {
        const float h0 = bf2f(hw[i] & 0xFFFFu);
        const float h1 = bf2f(hw[i] >> 16);
        const float g0 = bf2f(gw[i] & 0xFFFFu);
        const float g1 = bf2f(gw[i] >> 16);
        res[2 * i]     = fmaf(a, h0, fmaf(oma, g0, bp[2 * i]));
        res[2 * i + 1] = fmaf(a, h1, fmaf(oma, g1, bp[2 * i + 1]));
    }
    float* dst = &out[(size_t)e * 512 + lane * 8];
    *(float4*)(dst)     = make_float4(res[0], res[1], res[2], res[3]);
    *(float4*)(dst + 4) = make_float4(res[4], res[5], res[6], res[7]);

    // output 1: masked_idx as f32
    if (lane == 0) {
        out[(size_t)P * 512 + e] = (float)mi;
    }
}

extern "C" void kernel_launch(void* const* d_in, const int* in_sizes, int n_in,
                              void* d_out, int out_size, void* d_ws, size_t ws_size,
                              hipStream_t stream) {
    const float* h_mask = (const float*)d_in[0];
    const float* z      = (const float*)d_in[1];
    const float* Wq     = (const float*)d_in[2];
    const float* bq     = (const float*)d_in[3];
    const float* Wk     = (const float*)d_in[4];
    const float* bk     = (const float*)d_in[5];
    const float* W1     = (const float*)d_in[6];
    const float* b1     = (const float*)d_in[7];
    const float* W2     = (const float*)d_in[8];
    const float* b2     = (const float*)d_in[9];
    const float* Wpred  = (const float*)d_in[10];
    const float* bpred  = (const float*)d_in[11];
    const int* edge_index = (const int*)d_in[12];
    const int* node_ids   = (const int*)d_in[13];
    const int* masked_idx = (const int*)d_in[14];
    const int* edge_idx   = (const int*)d_in[15];

    const int N = in_sizes[13];
    const int P = in_sizes[14];

    // ---- workspace layout (peak 42.24 MB) ----
    // phase 1: [qb: N*256 bf16][kb: N*256 bf16]
    // phase 2: [hp: N*512 bf16 (overlays qb+kb)][gp: N*512 bf16][a: P f32]
    unsigned short* qb = (unsigned short*)d_ws;
    unsigned short* kb = qb + (size_t)N * 256;
    unsigned short* hp = (unsigned short*)d_ws;            // overlays qb..kb after edge_dot
    unsigned short* gp = kb + (size_t)N * 256;
    float*          a_arr = (float*)(gp + (size_t)N * 512);

    const dim3 blk(256);
    const int mb = (N + 15) / 16;
    const int eb = (P + 3) / 4;

    // q,k node tables (bf16)
    gemm_k256<16, true, false, true><<<dim3(mb, 1), blk, 0, stream>>>(z, Wq, bq, qb, N, 256);
    gemm_k256<16, true, false, true><<<dim3(mb, 1), blk, 0, stream>>>(z, Wk, bk, kb, N, 256);
    // per-edge sigmoid scalar
    edge_dot<<<dim3(eb), blk, 0, stream>>>(qb, kb, edge_index, node_ids, masked_idx, edge_idx, a_arr, P);
    // gp = MLP(z) @ Wpred (fused, bf16)
    fused_mlp_pred<16><<<dim3(mb), blk, 0, stream>>>(z, W1, b1, W2, b2, Wpred, gp, N);
    // hp = h_mask @ Wpred (bf16) — overlays dead qb/kb
    gemm_k256<16, false, false, true><<<dim3(mb, 2), blk, 0, stream>>>(h_mask, Wpred, nullptr, hp, N, 512);
    // final combine (f32 output)
    edge_combine<<<dim3(eb), blk, 0, stream>>>(a_arr, hp, gp, bpred,
                                               edge_index, node_ids, masked_idx, edge_idx,
                                               (float*)d_out, P);
}

// Round 4
// 426.770 us; speedup vs baseline: 1.6975x; 1.6975x over previous
//
#include <hip/hip_runtime.h>
#include <hip/hip_bf16.h>

typedef __attribute__((ext_vector_type(8))) short s16x8;
typedef __attribute__((ext_vector_type(4))) float f32x4;

__device__ inline float bf2f(unsigned int u16) {
    union { unsigned int i; float f; } v;
    v.i = u16 << 16;
    return v.f;
}
__device__ inline unsigned int f2bf(float f) {
    union { float f; unsigned int i; } v;
    v.f = f;
    return (v.i + 0x7FFFu + ((v.i >> 16) & 1u)) >> 16;   // RNE
}

// ---------- f32 -> bf16 cast, 8 elems/thread ----------
__global__ __launch_bounds__(256) void cvt_bf16(
    const float* __restrict__ in, unsigned short* __restrict__ out, int n8)
{
    const int i = blockIdx.x * 256 + threadIdx.x;
    if (i >= n8) return;
    const float4 a = *(const float4*)(in + (size_t)i * 8);
    const float4 b = *(const float4*)(in + (size_t)i * 8 + 4);
    uint4 r;
    r.x = f2bf(a.x) | (f2bf(a.y) << 16);
    r.y = f2bf(a.z) | (f2bf(a.w) << 16);
    r.z = f2bf(b.x) | (f2bf(b.y) << 16);
    r.w = f2bf(b.z) | (f2bf(b.w) << 16);
    *(uint4*)(out + (size_t)i * 8) = r;
}

// ---------- W[256][Nout] f32 -> Wt[Nout][256] bf16 (transpose+convert) ----------
__global__ __launch_bounds__(256) void tcvt(
    const float* __restrict__ W, unsigned short* __restrict__ Wt, int Nout, int total)
{
    const int i = blockIdx.x * 256 + threadIdx.x;
    if (i >= total) return;
    const int k = i / Nout, j = i % Nout;          // read coalesced
    Wt[(size_t)j * 256 + k] = (unsigned short)f2bf(W[i]);
}

// ---------- MFMA GEMM: out[M,Nout]bf16 = act(A[M,256]bf16 @ Wt^T + bias) ----------
// Wt is [Nout][256] (pre-transposed weights). Block: 64 rows, 4 waves (2x2),
// per-wave 32x32 C via 2x2 16x16x32 frags. A (32KB) + B-chunk (32KB) in LDS,
// XOR-swizzled (G4: row-major 512B rows would be a 16-way bank conflict).
template<bool BIAS, bool RELU>
__global__ __launch_bounds__(256) void gemm_mfma(
    const unsigned short* __restrict__ A, const unsigned short* __restrict__ Wt,
    const float* __restrict__ bias, unsigned short* __restrict__ out,
    int M, int Nout)
{
    __shared__ __align__(16) char smem[65536];
    char* ldsA = smem;
    char* ldsB = smem + 32768;
    const int tid  = threadIdx.x;
    const int wid  = tid >> 6, lane = tid & 63;
    const int wr   = wid >> 1, wc = wid & 1;
    const int r0   = blockIdx.x * 64;
    const int swz  = (lane & 7) << 4;

    // stage A: 64 rows x 512B, swizzled
    for (int i = tid; i < 2048; i += 256) {
        const int row = i >> 5, off = i & 31;
        const int gr = r0 + row;
        uint4 v = make_uint4(0, 0, 0, 0);
        if (gr < M) v = *(const uint4*)(A + (size_t)gr * 256 + off * 8);
        const int b = (row * 512 + off * 16) ^ ((row & 7) << 4);
        *(uint4*)(ldsA + b) = v;
    }

    // fragment base byte offsets (logical; swizzle applied per access)
    const int ro = lane & 15, ko = (lane >> 4) * 16;
    const int baseA0 = (wr * 32 +  0 + ro) * 512 + ko;
    const int baseA1 = (wr * 32 + 16 + ro) * 512 + ko;
    const int baseB0 = (wc * 32 +  0 + ro) * 512 + ko;
    const int baseB1 = (wc * 32 + 16 + ro) * 512 + ko;

    const int nchunks = Nout >> 6;
    for (int c = 0; c < nchunks; ++c) {
        const int j0 = c << 6;
        // stage B chunk: Wt rows j0..j0+63 (= output cols)
        for (int i = tid; i < 2048; i += 256) {
            const int row = i >> 5, off = i & 31;
            const uint4 v = *(const uint4*)(Wt + (size_t)(j0 + row) * 256 + off * 8);
            const int b = (row * 512 + off * 16) ^ ((row & 7) << 4);
            *(uint4*)(ldsB + b) = v;
        }
        __syncthreads();

        f32x4 acc00 = {0,0,0,0}, acc01 = {0,0,0,0}, acc10 = {0,0,0,0}, acc11 = {0,0,0,0};
#pragma unroll
        for (int kk = 0; kk < 8; ++kk) {
            const int kb = kk * 64;
            const s16x8 a0 = *(const s16x8*)(ldsA + ((baseA0 + kb) ^ swz));
            const s16x8 a1 = *(const s16x8*)(ldsA + ((baseA1 + kb) ^ swz));
            const s16x8 b0 = *(const s16x8*)(ldsB + ((baseB0 + kb) ^ swz));
            const s16x8 b1 = *(const s16x8*)(ldsB + ((baseB1 + kb) ^ swz));
            acc00 = __builtin_amdgcn_mfma_f32_16x16x32_bf16(a0, b0, acc00, 0, 0, 0);
            acc01 = __builtin_amdgcn_mfma_f32_16x16x32_bf16(a0, b1, acc01, 0, 0, 0);
            acc10 = __builtin_amdgcn_mfma_f32_16x16x32_bf16(a1, b0, acc10, 0, 0, 0);
            acc11 = __builtin_amdgcn_mfma_f32_16x16x32_bf16(a1, b1, acc11, 0, 0, 0);
        }

        // epilogue: bias/relu, bf16 store
        const int colb = j0 + wc * 32;
        float bs0 = 0.0f, bs1 = 0.0f;
        if (BIAS) { bs0 = bias[colb + ro]; bs1 = bias[colb + 16 + ro]; }
        const int rb0 = r0 + wr * 32 + (lane >> 4) * 4;
        const int rb1 = rb0 + 16;
#pragma unroll
        for (int r = 0; r < 4; ++r) {
            if (rb0 + r < M) {
                float v0 = acc00[r] + bs0, v1 = acc01[r] + bs1;
                if (RELU) { v0 = fmaxf(v0, 0.0f); v1 = fmaxf(v1, 0.0f); }
                out[(size_t)(rb0 + r) * Nout + colb + ro]      = (unsigned short)f2bf(v0);
                out[(size_t)(rb0 + r) * Nout + colb + 16 + ro] = (unsigned short)f2bf(v1);
            }
            if (rb1 + r < M) {
                float v0 = acc10[r] + bs0, v1 = acc11[r] + bs1;
                if (RELU) { v0 = fmaxf(v0, 0.0f); v1 = fmaxf(v1, 0.0f); }
                out[(size_t)(rb1 + r) * Nout + colb + ro]      = (unsigned short)f2bf(v0);
                out[(size_t)(rb1 + r) * Nout + colb + 16 + ro] = (unsigned short)f2bf(v1);
            }
        }
        __syncthreads();   // before next chunk overwrites ldsB
    }
}

// ---------- per-edge attention scalar: a[e] = sigmoid(q[c].k[s]) ----------
__global__ __launch_bounds__(256) void edge_dot(
    const unsigned short* __restrict__ qb, const unsigned short* __restrict__ kb,
    const int* __restrict__ edge_src, const int* __restrict__ node_ids,
    const int* __restrict__ masked_idx, const int* __restrict__ edge_idx,
    float* __restrict__ a_out, int P)
{
    const int wave = threadIdx.x >> 6;
    const int lane = threadIdx.x & 63;
    const int e = blockIdx.x * 4 + wave;
    if (e >= P) return;

    const int c = node_ids[masked_idx[e]];
    const int s = edge_src[edge_idx[e]];

    const uint2 qv = *(const uint2*)&qb[(size_t)c * 256 + lane * 4];
    const uint2 kv = *(const uint2*)&kb[(size_t)s * 256 + lane * 4];
    float dot = bf2f(qv.x & 0xFFFFu) * bf2f(kv.x & 0xFFFFu)
              + bf2f(qv.x >> 16)     * bf2f(kv.x >> 16)
              + bf2f(qv.y & 0xFFFFu) * bf2f(kv.y & 0xFFFFu)
              + bf2f(qv.y >> 16)     * bf2f(kv.y >> 16);
#pragma unroll
    for (int off = 32; off; off >>= 1) dot += __shfl_xor(dot, off, 64);

    if (lane == 0) a_out[e] = 1.0f / (1.0f + expf(-dot));
}

// ---------- edge combine: out[e,:] = a*hp[c,:] + (1-a)*gp[s,:] + bpred, f32 out ----------
__global__ __launch_bounds__(256) void edge_combine(
    const float* __restrict__ a_arr,
    const unsigned short* __restrict__ hp, const unsigned short* __restrict__ gp,
    const float* __restrict__ bpred,
    const int* __restrict__ edge_src, const int* __restrict__ node_ids,
    const int* __restrict__ masked_idx, const int* __restrict__ edge_idx,
    float* __restrict__ out, int P)
{
    const int wave = threadIdx.x >> 6;
    const int lane = threadIdx.x & 63;
    const int e = blockIdx.x * 4 + wave;
    if (e >= P) return;

    const int mi = masked_idx[e];
    const int c  = node_ids[mi];
    const int s  = edge_src[edge_idx[e]];

    const float a = a_arr[e];
    const float oma = 1.0f - a;

    const uint4 hv = *(const uint4*)&hp[(size_t)c * 512 + lane * 8];
    const uint4 gv = *(const uint4*)&gp[(size_t)s * 512 + lane * 8];
    const float4 bp0 = *(const float4*)&bpred[lane * 8];
    const float4 bp1 = *(const float4*)&bpred[lane * 8 + 4];

    const unsigned int hw[4] = {hv.x, hv.y, hv.z, hv.w};
    const unsigned int gw[4] = {gv.x, gv.y, gv.z, gv.w};
    const float bp[8] = {bp0.x, bp0.y, bp0.z, bp0.w, bp1.x, bp1.y, bp1.z, bp1.w};

    float res[8];
#pragma unroll
    for (int i = 0; i < 4; ++i) {
        const float h0 = bf2f(hw[i] & 0xFFFFu);
        const float h1 = bf2f(hw[i] >> 16);
        const float g0 = bf2f(gw[i] & 0xFFFFu);
        const float g1 = bf2f(gw[i] >> 16);
        res[2 * i]     = fmaf(a, h0, fmaf(oma, g0, bp[2 * i]));
        res[2 * i + 1] = fmaf(a, h1, fmaf(oma, g1, bp[2 * i + 1]));
    }
    float* dst = &out[(size_t)e * 512 + lane * 8];
    *(float4*)(dst)     = make_float4(res[0], res[1], res[2], res[3]);
    *(float4*)(dst + 4) = make_float4(res[4], res[5], res[6], res[7]);

    if (lane == 0) {
        out[(size_t)P * 512 + e] = (float)mi;
    }
}

extern "C" void kernel_launch(void* const* d_in, const int* in_sizes, int n_in,
                              void* d_out, int out_size, void* d_ws, size_t ws_size,
                              hipStream_t stream) {
    const float* h_mask = (const float*)d_in[0];
    const float* z      = (const float*)d_in[1];
    const float* Wq     = (const float*)d_in[2];
    const float* bq     = (const float*)d_in[3];
    const float* Wk     = (const float*)d_in[4];
    const float* bk     = (const float*)d_in[5];
    const float* W1     = (const float*)d_in[6];
    const float* b1     = (const float*)d_in[7];
    const float* W2     = (const float*)d_in[8];
    const float* b2     = (const float*)d_in[9];
    const float* Wpred  = (const float*)d_in[10];
    const float* bpred  = (const float*)d_in[11];
    const int* edge_index = (const int*)d_in[12];
    const int* node_ids   = (const int*)d_in[13];
    const int* masked_idx = (const int*)d_in[14];
    const int* edge_idx   = (const int*)d_in[15];

    const int N = in_sizes[13];
    const int P = in_sizes[14];

    // ---- workspace layout (~106 MB; ws is ~2.6 GB per poison-fill WRITE_SIZE) ----
    unsigned short* zb  = (unsigned short*)d_ws;
    unsigned short* hb  = zb  + (size_t)N * 256;
    unsigned short* qb  = hb  + (size_t)N * 256;
    unsigned short* kb  = qb  + (size_t)N * 256;
    unsigned short* tb  = kb  + (size_t)N * 256;
    unsigned short* gb  = tb  + (size_t)N * 256;
    unsigned short* gpb = gb  + (size_t)N * 256;
    unsigned short* hpb = gpb + (size_t)N * 512;
    unsigned short* Wtq = hpb + (size_t)N * 512;
    unsigned short* Wtk = Wtq + 65536;
    unsigned short* Wt1 = Wtk + 65536;
    unsigned short* Wt2 = Wt1 + 65536;
    unsigned short* Wtp = Wt2 + 65536;
    float*          a_arr = (float*)(Wtp + 131072);

    const dim3 blk(256);
    const int n8 = N * 256 / 8;
    const int cvtb = (n8 + 255) / 256;
    const int gb64 = (N + 63) / 64;
    const int eb = (P + 3) / 4;

    // prep: bf16 casts + transposed bf16 weights
    cvt_bf16<<<dim3(cvtb), blk, 0, stream>>>(z,      zb, n8);
    cvt_bf16<<<dim3(cvtb), blk, 0, stream>>>(h_mask, hb, n8);
    tcvt<<<dim3(256), blk, 0, stream>>>(Wq,    Wtq, 256, 65536);
    tcvt<<<dim3(256), blk, 0, stream>>>(Wk,    Wtk, 256, 65536);
    tcvt<<<dim3(256), blk, 0, stream>>>(W1,    Wt1, 256, 65536);
    tcvt<<<dim3(256), blk, 0, stream>>>(W2,    Wt2, 256, 65536);
    tcvt<<<dim3(512), blk, 0, stream>>>(Wpred, Wtp, 512, 131072);

    // node GEMMs (MFMA)
    gemm_mfma<true,  false><<<dim3(gb64), blk, 0, stream>>>(zb, Wtq, bq, qb, N, 256);
    gemm_mfma<true,  false><<<dim3(gb64), blk, 0, stream>>>(zb, Wtk, bk, kb, N, 256);
    edge_dot<<<dim3(eb), blk, 0, stream>>>(qb, kb, edge_index, node_ids, masked_idx, edge_idx, a_arr, P);
    gemm_mfma<true,  true ><<<dim3(gb64), blk, 0, stream>>>(zb, Wt1, b1, tb, N, 256);
    gemm_mfma<true,  false><<<dim3(gb64), blk, 0, stream>>>(tb, Wt2, b2, gb, N, 256);
    gemm_mfma<false, false><<<dim3(gb64), blk, 0, stream>>>(gb, Wtp, nullptr, gpb, N, 512);
    gemm_mfma<false, false><<<dim3(gb64), blk, 0, stream>>>(hb, Wtp, nullptr, hpb, N, 512);

    // edge combine (f32 output)
    edge_combine<<<dim3(eb), blk, 0, stream>>>(a_arr, hpb, gpb, bpred,
                                               edge_index, node_ids, masked_idx, edge_idx,
                                               (float*)d_out, P);
}

// Round 5
// 364.751 us; speedup vs baseline: 1.9861x; 1.1700x over previous
//
#include <hip/hip_runtime.h>
#include <hip/hip_bf16.h>

typedef __attribute__((ext_vector_type(8))) short s16x8;
typedef __attribute__((ext_vector_type(4))) float f32x4;

__device__ inline float bf2f(unsigned int u16) {
    union { unsigned int i; float f; } v;
    v.i = u16 << 16;
    return v.f;
}
__device__ inline unsigned int f2bf(float f) {
    union { float f; unsigned int i; } v;
    v.f = f;
    return (v.i + 0x7FFFu + ((v.i >> 16) & 1u)) >> 16;   // RNE
}

// ---------- fused prep: bf16 casts of z,h_mask + all weight transposes + bias concat ----------
// grid = 2*bz + 1024 + 512 + 2 blocks of 256
__global__ __launch_bounds__(256) void prep_all(
    const float* __restrict__ z, const float* __restrict__ h,
    const float* __restrict__ Wq, const float* __restrict__ Wk,
    const float* __restrict__ W1, const float* __restrict__ W2,
    const float* __restrict__ Wp,
    const float* __restrict__ bq, const float* __restrict__ bk,
    unsigned short* __restrict__ zb, unsigned short* __restrict__ hb,
    unsigned short* __restrict__ Wtqk, unsigned short* __restrict__ Wt1,
    unsigned short* __restrict__ Wt2, unsigned short* __restrict__ Wtp,
    float* __restrict__ bqk, int N)
{
    const int tid = threadIdx.x;
    const int bz = (N * 32 + 255) >> 8;
    int b = blockIdx.x;

    if (b < 2 * bz) {                       // f32 -> bf16 casts, 8 elems/thread
        const float* src = (b < bz) ? z : h;
        unsigned short* dst = (b < bz) ? zb : hb;
        const int i = (b % bz) * 256 + tid;
        if (i < N * 32) {
            const float4 a = *(const float4*)(src + (size_t)i * 8);
            const float4 c = *(const float4*)(src + (size_t)i * 8 + 4);
            uint4 r;
            r.x = f2bf(a.x) | (f2bf(a.y) << 16);
            r.y = f2bf(a.z) | (f2bf(a.w) << 16);
            r.z = f2bf(c.x) | (f2bf(c.y) << 16);
            r.w = f2bf(c.z) | (f2bf(c.w) << 16);
            *(uint4*)(dst + (size_t)i * 8) = r;
        }
        return;
    }
    b -= 2 * bz;
    if (b < 1024) {                         // 256x256 weights: Wq,Wk -> Wtqk halves; W1; W2
        const int w = b >> 8;
        const int i = (b & 255) * 256 + tid;
        const int k = i >> 8, j = i & 255;  // read coalesced over W[k][j]
        const float* W = (w == 0) ? Wq : (w == 1) ? Wk : (w == 2) ? W1 : W2;
        unsigned short* Wt = (w == 0) ? Wtqk : (w == 1) ? (Wtqk + 65536)
                              : (w == 2) ? Wt1 : Wt2;
        Wt[j * 256 + k] = (unsigned short)f2bf(W[i]);
        return;
    }
    b -= 1024;
    if (b < 512) {                          // Wpred [256][512] -> Wtp [512][256]
        const int i = b * 256 + tid;
        const int k = i >> 9, j = i & 511;
        Wtp[(size_t)j * 256 + k] = (unsigned short)f2bf(Wp[i]);
        return;
    }
    b -= 512;
    {                                       // bias concat bqk = [bq | bk]
        const int i = b * 256 + tid;
        bqk[i] = (i < 256) ? bq[i] : bk[i - 256];
    }
}

// ---------- MFMA GEMM: out[M,Nout]bf16 = act(A[M,256]bf16 @ Wt^T + bias) ----------
// Wt is [Nout][256]. Block: 64 rows, 4 waves (2x2), per-wave 32x32 C via 2x2
// 16x16x32 frags. A + B-chunk LDS-resident, XOR-swizzled (G4). Optional second
// (A,out) pair selected by blockIdx.y (shares Wt).
template<bool BIAS, bool RELU>
__global__ __launch_bounds__(256) void gemm_mfma(
    const unsigned short* __restrict__ A0, const unsigned short* __restrict__ A1,
    const unsigned short* __restrict__ Wt, const float* __restrict__ bias,
    unsigned short* __restrict__ out0, unsigned short* __restrict__ out1,
    int M, int Nout)
{
    __shared__ __align__(16) char smem[65536];
    char* ldsA = smem;
    char* ldsB = smem + 32768;
    const unsigned short* A = (blockIdx.y == 0) ? A0 : A1;
    unsigned short* out = (blockIdx.y == 0) ? out0 : out1;

    const int tid  = threadIdx.x;
    const int wid  = tid >> 6, lane = tid & 63;
    const int wr   = wid >> 1, wc = wid & 1;
    const int r0   = blockIdx.x * 64;
    const int swz  = (lane & 7) << 4;

    // stage A: 64 rows x 512B, swizzled
    for (int i = tid; i < 2048; i += 256) {
        const int row = i >> 5, off = i & 31;
        const int gr = r0 + row;
        uint4 v = make_uint4(0, 0, 0, 0);
        if (gr < M) v = *(const uint4*)(A + (size_t)gr * 256 + off * 8);
        const int b = (row * 512 + off * 16) ^ ((row & 7) << 4);
        *(uint4*)(ldsA + b) = v;
    }

    const int ro = lane & 15, ko = (lane >> 4) * 16;
    const int baseA0 = (wr * 32 +  0 + ro) * 512 + ko;
    const int baseA1 = (wr * 32 + 16 + ro) * 512 + ko;
    const int baseB0 = (wc * 32 +  0 + ro) * 512 + ko;
    const int baseB1 = (wc * 32 + 16 + ro) * 512 + ko;

    const int nchunks = Nout >> 6;
    for (int c = 0; c < nchunks; ++c) {
        const int j0 = c << 6;
        for (int i = tid; i < 2048; i += 256) {
            const int row = i >> 5, off = i & 31;
            const uint4 v = *(const uint4*)(Wt + (size_t)(j0 + row) * 256 + off * 8);
            const int b = (row * 512 + off * 16) ^ ((row & 7) << 4);
            *(uint4*)(ldsB + b) = v;
        }
        __syncthreads();

        f32x4 acc00 = {0,0,0,0}, acc01 = {0,0,0,0}, acc10 = {0,0,0,0}, acc11 = {0,0,0,0};
#pragma unroll
        for (int kk = 0; kk < 8; ++kk) {
            const int kb = kk * 64;
            const s16x8 a0 = *(const s16x8*)(ldsA + ((baseA0 + kb) ^ swz));
            const s16x8 a1 = *(const s16x8*)(ldsA + ((baseA1 + kb) ^ swz));
            const s16x8 b0 = *(const s16x8*)(ldsB + ((baseB0 + kb) ^ swz));
            const s16x8 b1 = *(const s16x8*)(ldsB + ((baseB1 + kb) ^ swz));
            acc00 = __builtin_amdgcn_mfma_f32_16x16x32_bf16(a0, b0, acc00, 0, 0, 0);
            acc01 = __builtin_amdgcn_mfma_f32_16x16x32_bf16(a0, b1, acc01, 0, 0, 0);
            acc10 = __builtin_amdgcn_mfma_f32_16x16x32_bf16(a1, b0, acc10, 0, 0, 0);
            acc11 = __builtin_amdgcn_mfma_f32_16x16x32_bf16(a1, b1, acc11, 0, 0, 0);
        }

        const int colb = j0 + wc * 32;
        float bs0 = 0.0f, bs1 = 0.0f;
        if (BIAS) { bs0 = bias[colb + ro]; bs1 = bias[colb + 16 + ro]; }
        const int rb0 = r0 + wr * 32 + (lane >> 4) * 4;
        const int rb1 = rb0 + 16;
#pragma unroll
        for (int r = 0; r < 4; ++r) {
            if (rb0 + r < M) {
                float v0 = acc00[r] + bs0, v1 = acc01[r] + bs1;
                if (RELU) { v0 = fmaxf(v0, 0.0f); v1 = fmaxf(v1, 0.0f); }
                out[(size_t)(rb0 + r) * Nout + colb + ro]      = (unsigned short)f2bf(v0);
                out[(size_t)(rb0 + r) * Nout + colb + 16 + ro] = (unsigned short)f2bf(v1);
            }
            if (rb1 + r < M) {
                float v0 = acc10[r] + bs0, v1 = acc11[r] + bs1;
                if (RELU) { v0 = fmaxf(v0, 0.0f); v1 = fmaxf(v1, 0.0f); }
                out[(size_t)(rb1 + r) * Nout + colb + ro]      = (unsigned short)f2bf(v0);
                out[(size_t)(rb1 + r) * Nout + colb + 16 + ro] = (unsigned short)f2bf(v1);
            }
        }
        __syncthreads();
    }
}

// ---------- fused edge kernel: a = sigmoid(q[c].k[s]); out = a*hp[c] + (1-a)*gp[s] + bpred ----------
// One wave per edge. qkb rows: [q(256) | k(256)] bf16.
__global__ __launch_bounds__(256) void edge_fused(
    const unsigned short* __restrict__ qkb,
    const unsigned short* __restrict__ hp, const unsigned short* __restrict__ gp,
    const float* __restrict__ bpred,
    const int* __restrict__ edge_src, const int* __restrict__ node_ids,
    const int* __restrict__ masked_idx, const int* __restrict__ edge_idx,
    float* __restrict__ out, int P)
{
    const int wave = threadIdx.x >> 6;
    const int lane = threadIdx.x & 63;
    const int e = blockIdx.x * 4 + wave;
    if (e >= P) return;

    const int mi = masked_idx[e];
    const int c  = node_ids[mi];
    const int s  = edge_src[edge_idx[e]];

    // dot(q[c], k[s]) across the wave (4 elems/lane)
    const uint2 qv = *(const uint2*)&qkb[(size_t)c * 512 + lane * 4];
    const uint2 kv = *(const uint2*)&qkb[(size_t)s * 512 + 256 + lane * 4];
    float dot = bf2f(qv.x & 0xFFFFu) * bf2f(kv.x & 0xFFFFu)
              + bf2f(qv.x >> 16)     * bf2f(kv.x >> 16)
              + bf2f(qv.y & 0xFFFFu) * bf2f(kv.y & 0xFFFFu)
              + bf2f(qv.y >> 16)     * bf2f(kv.y >> 16);
#pragma unroll
    for (int off = 32; off; off >>= 1) dot += __shfl_xor(dot, off, 64);

    const float a = 1.0f / (1.0f + expf(-dot));
    const float oma = 1.0f - a;

    const uint4 hv = *(const uint4*)&hp[(size_t)c * 512 + lane * 8];
    const uint4 gv = *(const uint4*)&gp[(size_t)s * 512 + lane * 8];
    const float4 bp0 = *(const float4*)&bpred[lane * 8];
    const float4 bp1 = *(const float4*)&bpred[lane * 8 + 4];

    const unsigned int hw[4] = {hv.x, hv.y, hv.z, hv.w};
    const unsigned int gw[4] = {gv.x, gv.y, gv.z, gv.w};
    const float bp[8] = {bp0.x, bp0.y, bp0.z, bp0.w, bp1.x, bp1.y, bp1.z, bp1.w};

    float res[8];
#pragma unroll
    for (int i = 0; i < 4; ++i) {
        const float h0 = bf2f(hw[i] & 0xFFFFu);
        const float h1 = bf2f(hw[i] >> 16);
        const float g0 = bf2f(gw[i] & 0xFFFFu);
        const float g1 = bf2f(gw[i] >> 16);
        res[2 * i]     = fmaf(a, h0, fmaf(oma, g0, bp[2 * i]));
        res[2 * i + 1] = fmaf(a, h1, fmaf(oma, g1, bp[2 * i + 1]));
    }
    float* dst = &out[(size_t)e * 512 + lane * 8];
    *(float4*)(dst)     = make_float4(res[0], res[1], res[2], res[3]);
    *(float4*)(dst + 4) = make_float4(res[4], res[5], res[6], res[7]);

    if (lane == 0) {
        out[(size_t)P * 512 + e] = (float)mi;
    }
}

extern "C" void kernel_launch(void* const* d_in, const int* in_sizes, int n_in,
                              void* d_out, int out_size, void* d_ws, size_t ws_size,
                              hipStream_t stream) {
    const float* h_mask = (const float*)d_in[0];
    const float* z      = (const float*)d_in[1];
    const float* Wq     = (const float*)d_in[2];
    const float* bq     = (const float*)d_in[3];
    const float* Wk     = (const float*)d_in[4];
    const float* bk     = (const float*)d_in[5];
    const float* W1     = (const float*)d_in[6];
    const float* b1     = (const float*)d_in[7];
    const float* W2     = (const float*)d_in[8];
    const float* b2     = (const float*)d_in[9];
    const float* Wpred  = (const float*)d_in[10];
    const float* bpred  = (const float*)d_in[11];
    const int* edge_index = (const int*)d_in[12];
    const int* node_ids   = (const int*)d_in[13];
    const int* masked_idx = (const int*)d_in[14];
    const int* edge_idx   = (const int*)d_in[15];

    const int N = in_sizes[13];
    const int P = in_sizes[14];

    // ---- workspace layout (~103 MB of the ~2.6 GB ws) ----
    unsigned short* zb   = (unsigned short*)d_ws;
    unsigned short* hb   = zb   + (size_t)N * 256;
    unsigned short* qkb  = hb   + (size_t)N * 256;   // [N][512] = q|k
    unsigned short* tb   = qkb  + (size_t)N * 512;
    unsigned short* gb   = tb   + (size_t)N * 256;
    unsigned short* gpb  = gb   + (size_t)N * 256;
    unsigned short* hpb  = gpb  + (size_t)N * 512;
    unsigned short* Wtqk = hpb  + (size_t)N * 512;   // [512][256]
    unsigned short* Wt1  = Wtqk + 131072;
    unsigned short* Wt2  = Wt1  + 65536;
    unsigned short* Wtp  = Wt2  + 65536;             // [512][256]
    float*          bqk  = (float*)(Wtp + 131072);   // [512]

    const dim3 blk(256);
    const int bz   = (N * 32 + 255) / 256;
    const int gb64 = (N + 63) / 64;
    const int eb   = (P + 3) / 4;

    // 1. all prep in one dispatch
    prep_all<<<dim3(2 * bz + 1024 + 512 + 2), blk, 0, stream>>>(
        z, h_mask, Wq, Wk, W1, W2, Wpred, bq, bk,
        zb, hb, Wtqk, Wt1, Wt2, Wtp, bqk, N);

    // 2. q|k in one GEMM (Nout=512)
    gemm_mfma<true, false><<<dim3(gb64, 1), blk, 0, stream>>>(zb, nullptr, Wtqk, bqk, qkb, nullptr, N, 512);
    // 3. t = relu(z@W1+b1)
    gemm_mfma<true, true ><<<dim3(gb64, 1), blk, 0, stream>>>(zb, nullptr, Wt1, b1, tb, nullptr, N, 256);
    // 4. g = t@W2+b2
    gemm_mfma<true, false><<<dim3(gb64, 1), blk, 0, stream>>>(tb, nullptr, Wt2, b2, gb, nullptr, N, 256);
    // 5. hp = h@Wpred, gp = g@Wpred (dual via blockIdx.y)
    gemm_mfma<false, false><<<dim3(gb64, 2), blk, 0, stream>>>(hb, gb, Wtp, nullptr, hpb, gpb, N, 512);

    // 6. fused edge phase (dot + sigmoid + combine + f32 store)
    edge_fused<<<dim3(eb), blk, 0, stream>>>(qkb, hpb, gpb, bpred,
                                             edge_index, node_ids, masked_idx, edge_idx,
                                             (float*)d_out, P);
}